// Round 1
// baseline (944.041 us; speedup 1.0000x reference)
//
#include <hip/hip_runtime.h>

typedef unsigned short u16;
typedef unsigned int u32;
typedef __attribute__((ext_vector_type(8))) short short8;
typedef __attribute__((ext_vector_type(4))) float f32x4;

#define N_NODES 10000
#define N_EDGES 100000
#define C_CH 64
#define S_SPH 16
#define NB_R 8
#define HID_D 64
#define NE_EL 10
#define G_GR 64
#define L_LAY 2
#define N_HEADS 1
#define RCUT 5.0f
#define INV_AVG (1.0f/16.0f)

__device__ __forceinline__ u16 f2bf(float f) {
  u32 u = __float_as_uint(f);
  u32 r = (u + 0x7FFFu + ((u >> 16) & 1u)) >> 16;
  return (u16)r;
}

__global__ void k_zero_out(float* out) {
  if (threadIdx.x < G_GR) out[threadIdx.x] = 0.0f;
}

__global__ void k_node_init(const float* __restrict__ attrs, const float* __restrict__ ae,
                            const int* __restrict__ batch, const int* __restrict__ head,
                            int* __restrict__ species, float* __restrict__ out) {
  int n = blockIdx.x * 256 + threadIdx.x;
  if (n >= N_NODES) return;
  int sp = 0;
#pragma unroll
  for (int e = 0; e < NE_EL; ++e)
    if (attrs[n * NE_EL + e] > 0.5f) sp = e;
  species[n] = sp;
  int b = batch[n];
  int h = head[b];
  atomicAdd(&out[b], ae[h * NE_EL + sp]);
}

__global__ void k_embed(const int* __restrict__ species, const float* __restrict__ Wemb,
                        float* __restrict__ feats) {
  int idx = blockIdx.x * 256 + threadIdx.x;
  if (idx >= N_NODES * C_CH) return;
  feats[idx] = Wemb[species[idx >> 6] * C_CH + (idx & 63)];
}

__global__ void k_geom(const float* __restrict__ pos, const float* __restrict__ shifts,
                       const int* __restrict__ ei, float* __restrict__ Y, float* __restrict__ rad) {
  int e = blockIdx.x * 256 + threadIdx.x;
  if (e >= N_EDGES) return;
  int s = ei[e], r = ei[N_EDGES + e];
  float dx = pos[r * 3 + 0] - pos[s * 3 + 0] + shifts[e * 3 + 0];
  float dy = pos[r * 3 + 1] - pos[s * 3 + 1] + shifts[e * 3 + 1];
  float dz = pos[r * 3 + 2] - pos[s * 3 + 2] + shifts[e * 3 + 2];
  float rr = sqrtf(dx * dx + dy * dy + dz * dz);
  rr = fmaxf(rr, 1e-12f);
  float inv = 1.0f / rr;
  float x = dx * inv, y = dy * inv, z = dz * inv;
  float xx = x * x, yy = y * y, zz = z * z;
  const float s3 = 1.73205080757f, s5 = 2.2360679775f, s15 = 3.87298334621f;
  const float c1 = 2.09165006634f, c2 = 10.2469507659f, c3 = 1.62018517461f;
  const float c4 = 1.32287565553f, c5 = 5.12347538298f;
  float4* Yo = (float4*)(Y + (size_t)e * 16);
  Yo[0] = make_float4(1.0f, s3 * x, s3 * y, s3 * z);
  Yo[1] = make_float4(s15 * x * y, s15 * y * z, 0.5f * s5 * (3.0f * zz - 1.0f), s15 * x * z);
  Yo[2] = make_float4(0.5f * s15 * (xx - yy), c1 * y * (3.0f * xx - yy), c2 * x * y * z,
                      c3 * y * (5.0f * zz - 1.0f));
  Yo[3] = make_float4(c4 * z * (5.0f * zz - 3.0f), c3 * x * (5.0f * zz - 1.0f),
                      c5 * z * (xx - yy), c1 * x * (xx - 3.0f * yy));
  // radial: sqrt(2/RC) * sin(n*pi*r/RC)/r * fcut(r)
  float t = rr * (1.0f / RCUT);
  float t2 = t * t;
  float t6 = t2 * t2 * t2;
  float fcut = 1.0f - 28.0f * t6 + 48.0f * t6 * t - 21.0f * t6 * t2;
  if (rr >= RCUT) fcut = 0.0f;
  float pref = 0.63245553203f * inv * fcut;
  float arg = 3.14159265359f * rr * (1.0f / RCUT);
  float sa, ca;
  __sincosf(arg, &sa, &ca);
  float twoc = 2.0f * ca;
  float sprev = 0.0f, scur = sa;
  float rv[8];
#pragma unroll
  for (int n = 0; n < 8; ++n) {
    rv[n] = pref * scur;
    float snext = twoc * scur - sprev;
    sprev = scur;
    scur = snext;
  }
  float4* Ro = (float4*)(rad + (size_t)e * 8);
  Ro[0] = make_float4(rv[0], rv[1], rv[2], rv[3]);
  Ro[1] = make_float4(rv[4], rv[5], rv[6], rv[7]);
}

__global__ void k_w3cast(const float* __restrict__ w3, u16* __restrict__ w3b) {
  int idx = blockIdx.x * 256 + threadIdx.x;
  if (idx >= L_LAY * HID_D * C_CH * S_SPH) return;
  w3b[idx] = f2bf(w3[idx]);
}

__global__ void __launch_bounds__(256) k_edge_mlp(const float* __restrict__ rad,
                                                  const float* __restrict__ w1,
                                                  const float* __restrict__ w2,
                                                  u16* __restrict__ h2) {
  __shared__ float w1s[NB_R * HID_D];
  __shared__ float w2s[HID_D * HID_D];
  __shared__ float h1s[4][HID_D];
  int tid = threadIdx.x;
  for (int i = tid; i < NB_R * HID_D; i += 256) w1s[i] = w1[i];
  for (int i = tid; i < HID_D * HID_D; i += 256) w2s[i] = w2[i];
  __syncthreads();
  int slot = tid >> 6, t = tid & 63;
  for (int eb = blockIdx.x * 4; eb < N_EDGES; eb += gridDim.x * 4) {
    int e = eb + slot;
    float pre = 0.0f;
#pragma unroll
    for (int k = 0; k < NB_R; ++k) pre += rad[e * NB_R + k] * w1s[k * HID_D + t];
    float h1 = pre / (1.0f + __expf(-pre));
    h1s[slot][t] = h1;
    __syncthreads();
    float pre2 = 0.0f;
#pragma unroll
    for (int j = 0; j < HID_D; ++j) pre2 += h1s[slot][j] * w2s[j * HID_D + t];
    float h2v = pre2 / (1.0f + __expf(-pre2));
    h2[(size_t)e * HID_D + t] = f2bf(h2v);
    __syncthreads();
  }
}

__global__ void __launch_bounds__(256) k_up(const float* __restrict__ feats,
                                            const float* __restrict__ Wup,
                                            float* __restrict__ up) {
  __shared__ float ws[C_CH * C_CH];
  __shared__ float fs[4][C_CH];
  int tid = threadIdx.x;
  for (int i = tid; i < C_CH * C_CH; i += 256) ws[i] = Wup[i];
  __syncthreads();
  int slot = tid >> 6, t = tid & 63;
  for (int nb = blockIdx.x * 4; nb < N_NODES; nb += gridDim.x * 4) {
    int n = nb + slot;
    fs[slot][t] = feats[n * C_CH + t];
    __syncthreads();
    float acc = 0.0f;
#pragma unroll
    for (int j = 0; j < C_CH; ++j) acc += fs[slot][j] * ws[j * C_CH + t];
    up[n * C_CH + t] = acc;
    __syncthreads();
  }
}

__global__ void k_zeroA(float4* __restrict__ A) {
  int tot = N_NODES * C_CH * S_SPH / 4;
  for (int i = blockIdx.x * 256 + threadIdx.x; i < tot; i += gridDim.x * 256)
    A[i] = make_float4(0.0f, 0.0f, 0.0f, 0.0f);
}

// 16-edge tile: tp_w via bf16 MFMA, fused epilogue msg scatter into Abuf.
__global__ void __launch_bounds__(256) k_scatter(const u16* __restrict__ h2,
                                                 const u16* __restrict__ W3b,
                                                 const float* __restrict__ up,
                                                 const float* __restrict__ Y,
                                                 const int* __restrict__ ei,
                                                 float* __restrict__ Abuf) {
  __shared__ __align__(16) u16 h2s[16][64];
  __shared__ float ups[16][64];
  __shared__ float Ys[16][16];
  __shared__ int recvs[16];
  int tid = threadIdx.x;
  int eb = blockIdx.x * 16;
  {
    const u32* src = (const u32*)(h2 + (size_t)eb * 64);
    u32* dst = (u32*)&h2s[0][0];
    dst[tid] = src[tid];
    dst[tid + 256] = src[tid + 256];
  }
  for (int idx = tid; idx < 1024; idx += 256) {
    int i = idx >> 6, c = idx & 63;
    int snd = ei[eb + i];
    ups[i][c] = up[snd * C_CH + c];
  }
  {
    int i = tid >> 4, s = tid & 15;
    Ys[i][s] = Y[(size_t)(eb + i) * 16 + s];
  }
  if (tid < 16) recvs[tid] = ei[N_EDGES + eb + tid];
  __syncthreads();
  int lane = tid & 63, wv = tid >> 6;
  int row = lane & 15, kg = lane >> 4;
  short8 a0 = *(const short8*)&h2s[row][kg * 8];
  short8 a1 = *(const short8*)&h2s[row][32 + kg * 8];
  int col = lane & 15;
#pragma unroll 4
  for (int t = 0; t < 16; ++t) {
    int nb = wv * 16 + t;  // channel index c (cs = nb*16 + s)
    const u16* Wcol = W3b + nb * 16 + col;
    short8 b0, b1;
#pragma unroll
    for (int j = 0; j < 8; ++j) {
      b0[j] = (short)Wcol[(kg * 8 + j) * 1024];
      b1[j] = (short)Wcol[(32 + kg * 8 + j) * 1024];
    }
    f32x4 acc = {0.0f, 0.0f, 0.0f, 0.0f};
    acc = __builtin_amdgcn_mfma_f32_16x16x32_bf16(a0, b0, acc, 0, 0, 0);
    acc = __builtin_amdgcn_mfma_f32_16x16x32_bf16(a1, b1, acc, 0, 0, 0);
#pragma unroll
    for (int r4 = 0; r4 < 4; ++r4) {
      int ie = kg * 4 + r4;  // D row = edge-in-tile
      float v = acc[r4] * ups[ie][nb] * Ys[ie][col] * INV_AVG;
      if (v != 0.0f) atomicAdd(&Abuf[(size_t)recvs[ie] * 1024 + nb * 16 + col], v);
    }
  }
}

__global__ void __launch_bounds__(256) k_node_update(
    const float* __restrict__ Abuf, const float* __restrict__ featsOld,
    float* __restrict__ featsNew, const float* __restrict__ Wmix,
    const float* __restrict__ Wskip, const float* __restrict__ Wc,
    const float* __restrict__ Wout, const float* __restrict__ Wro,
    const int* __restrict__ species, const int* __restrict__ batch,
    const int* __restrict__ headArr, float* __restrict__ out) {
  __shared__ float Wmixs[C_CH * C_CH];
  __shared__ float Wouts[C_CH * C_CH];
  __shared__ __align__(16) float As[4 * C_CH * S_SPH];
  __shared__ float qs[4][C_CH];
  int tid = threadIdx.x;
  for (int i = tid; i < C_CH * C_CH; i += 256) {
    Wmixs[i] = Wmix[i];
    Wouts[i] = Wout[i];
  }
  size_t base = (size_t)blockIdx.x * 4 * C_CH * S_SPH;
  for (int i = tid; i < 4 * C_CH * S_SPH; i += 256) As[i] = Abuf[base + i];
  __syncthreads();
  int nl = tid >> 6, t = tid & 63;
  int node = blockIdx.x * 4 + nl;
  int sp = species[node];
  float A2[S_SPH];
#pragma unroll
  for (int s = 0; s < S_SPH; ++s) A2[s] = 0.0f;
  const float4* Ac = (const float4*)&As[nl * C_CH * S_SPH];
  for (int c = 0; c < C_CH; ++c) {
    float wm = Wmixs[c * C_CH + t];
    float4 v0 = Ac[c * 4 + 0], v1 = Ac[c * 4 + 1], v2 = Ac[c * 4 + 2], v3 = Ac[c * 4 + 3];
    A2[0] += wm * v0.x; A2[1] += wm * v0.y; A2[2] += wm * v0.z; A2[3] += wm * v0.w;
    A2[4] += wm * v1.x; A2[5] += wm * v1.y; A2[6] += wm * v1.z; A2[7] += wm * v1.w;
    A2[8] += wm * v2.x; A2[9] += wm * v2.y; A2[10] += wm * v2.z; A2[11] += wm * v2.w;
    A2[12] += wm * v3.x; A2[13] += wm * v3.y; A2[14] += wm * v3.z; A2[15] += wm * v3.w;
  }
  float p1 = A2[0];
  float p2 = 0.0f;
#pragma unroll
  for (int s = 0; s < S_SPH; ++s) p2 += A2[s] * A2[s];
  float p3 = p2 * p1;
  float q = Wc[(sp * 3 + 0) * C_CH + t] * p1 + Wc[(sp * 3 + 1) * C_CH + t] * p2 +
            Wc[(sp * 3 + 2) * C_CH + t] * p3;
  qs[nl][t] = q;
  float sc = 0.0f;
  for (int c = 0; c < C_CH; ++c)
    sc += featsOld[node * C_CH + c] * Wskip[(c * NE_EL + sp) * C_CH + t];
  __syncthreads();
  float nf = sc;
#pragma unroll
  for (int d = 0; d < C_CH; ++d) nf += qs[nl][d] * Wouts[d * C_CH + t];
  featsNew[node * C_CH + t] = nf;
  int b = batch[node];
  int h = headArr[b];
  float en = nf * Wro[t * N_HEADS + h];
#pragma unroll
  for (int off = 32; off; off >>= 1) en += __shfl_down(en, off, 64);
  if (t == 0) atomicAdd(&out[b], en);
}

extern "C" void kernel_launch(void* const* d_in, const int* in_sizes, int n_in,
                              void* d_out, int out_size, void* d_ws, size_t ws_size,
                              hipStream_t stream) {
  const float* pos = (const float*)d_in[0];
  const float* attrs = (const float*)d_in[1];
  const float* shifts = (const float*)d_in[2];
  const float* ae = (const float*)d_in[3];
  const float* Wemb = (const float*)d_in[4];
  const float* Wup = (const float*)d_in[5];
  const float* w1 = (const float*)d_in[6];
  const float* w2 = (const float*)d_in[7];
  const float* w3 = (const float*)d_in[8];
  const float* Wmix = (const float*)d_in[9];
  const float* Wskip = (const float*)d_in[10];
  const float* Wc = (const float*)d_in[11];
  const float* Wout = (const float*)d_in[12];
  const float* Wro = (const float*)d_in[13];
  const int* ei = (const int*)d_in[14];
  const int* batch = (const int*)d_in[15];
  const int* head = (const int*)d_in[16];
  float* out = (float*)d_out;

  char* p = (char*)d_ws;
  float* Y = (float*)p;      p += (size_t)N_EDGES * 16 * 4;
  float* rad = (float*)p;    p += (size_t)N_EDGES * 8 * 4;
  float* up = (float*)p;     p += (size_t)N_NODES * 64 * 4;
  float* fA = (float*)p;     p += (size_t)N_NODES * 64 * 4;
  float* fB = (float*)p;     p += (size_t)N_NODES * 64 * 4;
  float* Abuf = (float*)p;   p += (size_t)N_NODES * 1024 * 4;
  u16* h2 = (u16*)p;         p += (size_t)N_EDGES * 64 * 2;
  u16* W3b = (u16*)p;        p += (size_t)L_LAY * 65536 * 2;
  int* species = (int*)p;    p += (size_t)N_NODES * 4;
  if ((size_t)(p - (char*)d_ws) > ws_size) return;  // insufficient workspace guard

  k_zero_out<<<1, 64, 0, stream>>>(out);
  k_node_init<<<(N_NODES + 255) / 256, 256, 0, stream>>>(attrs, ae, batch, head, species, out);
  k_embed<<<(N_NODES * C_CH + 255) / 256, 256, 0, stream>>>(species, Wemb, fA);
  k_geom<<<(N_EDGES + 255) / 256, 256, 0, stream>>>(pos, shifts, ei, Y, rad);
  k_w3cast<<<(L_LAY * 65536 + 255) / 256, 256, 0, stream>>>(w3, W3b);

  const float* fOld = fA;
  float* fNew = fB;
  for (int l = 0; l < L_LAY; ++l) {
    k_edge_mlp<<<1024, 256, 0, stream>>>(rad, w1 + l * NB_R * HID_D, w2 + l * HID_D * HID_D, h2);
    k_up<<<512, 256, 0, stream>>>(fOld, Wup + l * C_CH * C_CH, up);
    k_zeroA<<<2048, 256, 0, stream>>>((float4*)Abuf);
    k_scatter<<<N_EDGES / 16, 256, 0, stream>>>(h2, W3b + l * 65536, up, Y, ei, Abuf);
    k_node_update<<<N_NODES / 4, 256, 0, stream>>>(
        Abuf, fOld, fNew, Wmix + l * C_CH * C_CH, Wskip + l * C_CH * NE_EL * C_CH,
        Wc + l * NE_EL * 3 * C_CH, Wout + l * C_CH * C_CH, Wro + l * C_CH * N_HEADS,
        species, batch, head, out);
    const float* tmp = fNew;
    fNew = (float*)fOld;
    fOld = tmp;
  }
}